// Round 2
// baseline (77.854 us; speedup 1.0000x reference)
//
#include <hip/hip_runtime.h>

// ConvCNP fused kernel for MI355X (gfx950).
// B=4, N=2048, M=8192, C=2 (density + 1 conv channel), COUT=64.
//
// Roofline note: irreducible work is B*M*N = 67.1M v_exp_f32 (one per (m,n),
// shared by both channels when sigma[0]==sigma[1]). At 8 cy/wave64 on the
// trans pipe that is ~3.4 us across 1024 SIMDs; everything else (2 pk-ops/exp
// VALU, conflict-free ds_read, 8 MB store) hides under or adds ~1-2 us.
#define NB    4
#define NN    2048
#define NM    8192
#define NCOUT 64

typedef float v2f __attribute__((ext_vector_type(2)));

__device__ __forceinline__ float fexp2(float x) {
#if defined(__has_builtin)
#if __has_builtin(__builtin_amdgcn_exp2f)
    return __builtin_amdgcn_exp2f(x);   // v_exp_f32 (2^x); -x folds into src neg modifier
#else
    return exp2f(x);
#endif
#else
    return exp2f(x);
#endif
}

// block = 256 (4 waves). Each wave reduces over all N for FOUR target points m.
// Block covers 16 m. grid.x = NB*NM/16 = 2048 -> exactly 8 blocks/CU resident
// (32 waves/CU = full wave slots; 8 x 16 KB LDS = 128 KB <= 160 KB).
__global__ __launch_bounds__(256) void convcnp_kernel(
    const float* __restrict__ ci,    // context_in  (B,N,1)
    const float* __restrict__ co,    // context_out (B,N,1)
    const float* __restrict__ ti,    // target_in   (B,M,1)
    const float* __restrict__ sigma, // (2,)
    const float* __restrict__ W,     // (64,2) row-major
    const float* __restrict__ bias,  // (64,)
    float* __restrict__ out)         // (B,M,64)
{
    // Packed as float4 = (x_{2i}, y_{2i}, x_{2i+1}, y_{2i+1}) so the main loop
    // uses one ds_read_b128 per TWO context points (was 2x ds_read_b64).
    __shared__ float4 sxy[NN / 2];
    const int tid   = threadIdx.x;
    const int b     = blockIdx.x >> 9;          // 512 blocks per batch
    const int mbase = (blockIdx.x & 511) * 16;

    const float4* ci4 = (const float4*)(ci + (size_t)b * NN);
    const float4* co4 = (const float4*)(co + (size_t)b * NN);
    #pragma unroll
    for (int i = tid; i < NN / 4; i += 256) {
        float4 x = ci4[i];
        float4 y = co4[i];
        sxy[2 * i + 0] = make_float4(x.x, y.x, x.y, y.y);
        sxy[2 * i + 1] = make_float4(x.z, y.z, x.w, y.w);
    }

    // w_c = exp(-0.5 d^2 / exp(2*sigma_c)) = exp2(-(r_c*d)^2), r_c = sqrt(0.5*log2e*exp(-2*sigma_c))
    const float LOG2E = 1.4426950408889634f;
    const float s0 = sigma[0], s1 = sigma[1];
    const float r0 = sqrtf(0.5f * LOG2E * __expf(-2.0f * s0));
    const float r1 = sqrtf(0.5f * LOG2E * __expf(-2.0f * s1));
    __syncthreads();

    const int wave = tid >> 6;
    const int lane = tid & 63;
    const int m0   = mbase + wave * 4;
    const float* tb = ti + (size_t)b * NM + m0;
    const float t0 = tb[0], t1 = tb[1], t2 = tb[2], t3 = tb[3];

    v2f den01 = {0.f, 0.f}, den23 = {0.f, 0.f};
    v2f cv01  = {0.f, 0.f}, cv23  = {0.f, 0.f};

    if (s0 == s1) {
        // sigma[0]==sigma[1] (the actual case): one exp serves both channels.
        const v2f r2    = {r0, r0};
        const v2f nrt01 = {-r0 * t0, -r0 * t1};
        const v2f nrt23 = {-r0 * t2, -r0 * t3};
        #pragma unroll 2
        for (int i = lane; i < NN / 2; i += 64) {
            float4 q = sxy[i];           // two context points per ds_read_b128
            {   // n = 2i
                v2f x2 = {q.x, q.x};
                v2f y2 = {q.y, q.y};
                v2f e01 = x2 * r2 + nrt01;   // v_pk_fma_f32
                v2f e23 = x2 * r2 + nrt23;
                v2f f01 = e01 * e01;         // v_pk_mul_f32
                v2f f23 = e23 * e23;
                v2f w01, w23;
                w01.x = fexp2(-f01.x);       // v_exp_f32 with neg src modifier
                w01.y = fexp2(-f01.y);
                w23.x = fexp2(-f23.x);
                w23.y = fexp2(-f23.y);
                den01 += w01;                // v_pk_add_f32
                den23 += w23;
                cv01 = w01 * y2 + cv01;      // v_pk_fma_f32
                cv23 = w23 * y2 + cv23;
            }
            {   // n = 2i+1
                v2f x2 = {q.z, q.z};
                v2f y2 = {q.w, q.w};
                v2f e01 = x2 * r2 + nrt01;
                v2f e23 = x2 * r2 + nrt23;
                v2f f01 = e01 * e01;
                v2f f23 = e23 * e23;
                v2f w01, w23;
                w01.x = fexp2(-f01.x);
                w01.y = fexp2(-f01.y);
                w23.x = fexp2(-f23.x);
                w23.y = fexp2(-f23.y);
                den01 += w01;
                den23 += w23;
                cv01 = w01 * y2 + cv01;
                cv23 = w23 * y2 + cv23;
            }
        }
    } else {
        // General path: density uses scale0, conv uses scale1. (Not taken for
        // the bench inputs; kept correct via a float2 view of the LDS tile.)
        const float2* sxy2 = (const float2*)sxy;
        const float a0 = -r0 * t0, a1 = -r0 * t1, a2 = -r0 * t2, a3 = -r0 * t3;
        const float b0 = -r1 * t0, b1 = -r1 * t1, b2 = -r1 * t2, b3 = -r1 * t3;
        #pragma unroll 2
        for (int n = lane; n < NN; n += 64) {
            float2 xy = sxy2[n];
            const float x = xy.x, y = xy.y;
            float ea0 = fmaf(r0, x, a0), ea1 = fmaf(r0, x, a1);
            float ea2 = fmaf(r0, x, a2), ea3 = fmaf(r0, x, a3);
            float eb0 = fmaf(r1, x, b0), eb1 = fmaf(r1, x, b1);
            float eb2 = fmaf(r1, x, b2), eb3 = fmaf(r1, x, b3);
            den01.x += fexp2(-ea0 * ea0); den01.y += fexp2(-ea1 * ea1);
            den23.x += fexp2(-ea2 * ea2); den23.y += fexp2(-ea3 * ea3);
            cv01.x = fmaf(fexp2(-eb0 * eb0), y, cv01.x);
            cv01.y = fmaf(fexp2(-eb1 * eb1), y, cv01.y);
            cv23.x = fmaf(fexp2(-eb2 * eb2), y, cv23.x);
            cv23.y = fmaf(fexp2(-eb3 * eb3), y, cv23.y);
        }
    }

    // Merged-tree 64-lane reduction of 8 independent sums.
    // R1 lesson: every __shfl_xor MUST be an unconditional top-level statement.
    // Shuffles inside ternary operands get compiled as divergent branches
    // (convergent intrinsics can't be speculated), and ds_bpermute reading
    // from an exec-masked-off lane returns garbage -> absmax 544 failure.
    // Here: all shuffles full-exec; the lane-parity selection is a pure
    // float v_cndmask AFTER the cross-lane data is already in registers.
    //
    // Fold pairs into lane-parity slots at offsets 1/2/4 (halving live values
    // each step), then 3 plain butterflies. After the tree, the FULL sum of
    // value v lives on lanes with (lane&7)==v,
    // v: 0=den0 1=cv0 2=den1 3=cv1 4=den2 5=cv2 6=den3 7=cv3.
    const bool p1 = lane & 1, p2 = lane & 2, p4 = lane & 4;

    const float sd0 = __shfl_xor(den01.x, 1);
    const float sc0 = __shfl_xor(cv01.x, 1);
    const float sd1 = __shfl_xor(den01.y, 1);
    const float sc1 = __shfl_xor(cv01.y, 1);
    const float sd2 = __shfl_xor(den23.x, 1);
    const float sc2 = __shfl_xor(cv23.x, 1);
    const float sd3 = __shfl_xor(den23.y, 1);
    const float sc3 = __shfl_xor(cv23.y, 1);
    const float rdc0 = p1 ? (cv01.x + sc0) : (den01.x + sd0);
    const float rdc1 = p1 ? (cv01.y + sc1) : (den01.y + sd1);
    const float rdc2 = p1 ? (cv23.x + sc2) : (den23.x + sd2);
    const float rdc3 = p1 ? (cv23.y + sc3) : (den23.y + sd3);

    const float sa0 = __shfl_xor(rdc0, 2);
    const float sa1 = __shfl_xor(rdc1, 2);
    const float sb0 = __shfl_xor(rdc2, 2);
    const float sb1 = __shfl_xor(rdc3, 2);
    const float ra = p2 ? (rdc1 + sa1) : (rdc0 + sa0);
    const float rb = p2 ? (rdc3 + sb1) : (rdc2 + sb0);

    const float sra = __shfl_xor(ra, 4);
    const float srb = __shfl_xor(rb, 4);
    float r = p4 ? (rb + srb) : (ra + sra);

    r += __shfl_xor(r, 8);
    r += __shfl_xor(r, 16);
    r += __shfl_xor(r, 32);

    // Broadcast the 8 totals to all lanes (all lanes need all of them:
    // lane j is output channel j for every m).
    const float den[4] = {__shfl(r, 0), __shfl(r, 2), __shfl(r, 4), __shfl(r, 6)};
    const float cv[4]  = {__shfl(r, 1), __shfl(r, 3), __shfl(r, 5), __shfl(r, 7)};

    // Epilogue: out = [density, conv/(density+eps)] @ W^T + b. Lane j = channel j.
    const float EPSF = 1e-8f;
    const float w0 = W[2 * lane], w1 = W[2 * lane + 1], bb = bias[lane];
    float* ob = out + ((size_t)b * NM + m0) * NCOUT + lane;
    #pragma unroll
    for (int k = 0; k < 4; ++k) {
        const float conv = cv[k] / (den[k] + EPSF);
        ob[(size_t)k * NCOUT] = fmaf(den[k], w0, fmaf(conv, w1, bb));
    }
}

extern "C" void kernel_launch(void* const* d_in, const int* in_sizes, int n_in,
                              void* d_out, int out_size, void* d_ws, size_t ws_size,
                              hipStream_t stream) {
    const float* ci    = (const float*)d_in[0];
    const float* co    = (const float*)d_in[1];
    const float* ti    = (const float*)d_in[2];
    const float* sigma = (const float*)d_in[3];
    const float* W     = (const float*)d_in[4];
    const float* bias  = (const float*)d_in[5];
    float* out = (float*)d_out;

    dim3 grid(NB * NM / 16);  // 2048 blocks
    dim3 block(256);
    hipLaunchKernelGGL(convcnp_kernel, grid, block, 0, stream,
                       ci, co, ti, sigma, W, bias, out);
}